// Round 7
// baseline (491.494 us; speedup 1.0000x reference)
//
#include <hip/hip_runtime.h>
#include <math.h>
#include <stdint.h>

typedef unsigned short u16;
typedef unsigned int u32;

typedef __attribute__((ext_vector_type(8))) short bf16x8;
typedef __attribute__((ext_vector_type(4))) float f32x4;

#define ASYNC_COPY16(g, l)                                                         \
  __builtin_amdgcn_global_load_lds((__attribute__((address_space(1))) const void*)(g), \
                                   (__attribute__((address_space(3))) void*)(l), 16, 0, 0)

__device__ __forceinline__ float bf2f(u16 u) {
  union { u32 i; float f; } v; v.i = ((u32)u) << 16; return v.f;
}
__device__ __forceinline__ u16 f2bf(float f) {
  union { float f; u32 i; } v; v.f = f;
  u32 r = v.i + 0x7fffu + ((v.i >> 16) & 1u);
  return (u16)(r >> 16);
}
// fast GELU (tanh form via sigmoid): x*sigmoid(1.5957691*(x+0.044715*x^3))
__device__ __forceinline__ float gelu_fast(float x) {
  float t = x * x;
  float z = 1.5957691f * x * (1.0f + 0.044715f * t);
  return x / (1.0f + __expf(-z));
}

// ---------------------------------------------------------------------------
// K0: fused f32->bf16 conversion of all 4 weight tensors into ONE contiguous
// bf16 region (w1b | w2b | ew1b | ew2b).
// ---------------------------------------------------------------------------
__global__ __launch_bounds__(256) void cvt_all_k(
    const float* __restrict__ s0, const float* __restrict__ s1,
    const float* __restrict__ s2, const float* __restrict__ s3,
    u16* __restrict__ dst)
{
  const int64_t i0 = (int64_t)blockIdx.x * 2048 + (int64_t)threadIdx.x * 8;
  const float* src; int64_t rel;
  if (i0 < 2097152)       { src = s0; rel = i0; }
  else if (i0 < 4194304)  { src = s1; rel = i0 - 2097152; }
  else if (i0 < 20971520) { src = s2; rel = i0 - 4194304; }
  else                    { src = s3; rel = i0 - 20971520; }
  const float4 a = *(const float4*)(src + rel);
  const float4 b = *(const float4*)(src + rel + 4);
  union { u16 h[8]; uint4 v; } o;
  o.h[0] = f2bf(a.x); o.h[1] = f2bf(a.y); o.h[2] = f2bf(a.z); o.h[3] = f2bf(a.w);
  o.h[4] = f2bf(b.x); o.h[5] = f2bf(b.y); o.h[6] = f2bf(b.z); o.h[7] = f2bf(b.w);
  *(uint4*)(dst + i0) = o.v;
}

// ---------------------------------------------------------------------------
// K1: LayerNorm + router + top-2, WAVE-PER-TOKEN (4 tokens/block, zero
// __syncthreads — round-6 accounting put ~60-100us in the block-per-token
// barrier/reduction structure). All reductions are intra-wave shuffles.
// ---------------------------------------------------------------------------
__global__ __launch_bounds__(256) void ln_router_k(
    const float* __restrict__ x, const float* __restrict__ g, const float* __restrict__ b,
    const float* __restrict__ rw, const float* __restrict__ rb,
    u16* __restrict__ xn, int* __restrict__ tk_idx, float* __restrict__ tk_w)
{
  __shared__ float xs[4][1024];
  const int wave = threadIdx.x >> 6, lane = threadIdx.x & 63;
  const int t = blockIdx.x * 4 + wave;

  const float* xrow = x + (size_t)t * 1024;
  float4 v[4];
#pragma unroll
  for (int j = 0; j < 4; ++j) v[j] = *(const float4*)(xrow + lane * 4 + j * 256);
  float s = 0.f, q = 0.f;
#pragma unroll
  for (int j = 0; j < 4; ++j) {
    s += v[j].x + v[j].y + v[j].z + v[j].w;
    q += v[j].x * v[j].x + v[j].y * v[j].y + v[j].z * v[j].z + v[j].w * v[j].w;
  }
#pragma unroll
  for (int o = 32; o > 0; o >>= 1) { s += __shfl_down(s, o, 64); q += __shfl_down(q, o, 64); }
  s = __shfl(s, 0, 64); q = __shfl(q, 0, 64);
  const float mean = s * (1.0f / 1024.0f);
  const float rstd = rsqrtf(q * (1.0f / 1024.0f) - mean * mean + 1e-5f);

#pragma unroll
  for (int j = 0; j < 4; ++j) {
    const int d0 = lane * 4 + j * 256;
    const float4 gv = *(const float4*)(g + d0);
    const float4 bv = *(const float4*)(b + d0);
    float y0 = (v[j].x - mean) * rstd * gv.x + bv.x;
    float y1 = (v[j].y - mean) * rstd * gv.y + bv.y;
    float y2 = (v[j].z - mean) * rstd * gv.z + bv.z;
    float y3 = (v[j].w - mean) * rstd * gv.w + bv.w;
    float4 yv = {y0, y1, y2, y3};
    *(float4*)(&xs[wave][d0]) = yv;
    union { u16 h[4]; uint2 u; } pk;
    pk.h[0] = f2bf(y0); pk.h[1] = f2bf(y1); pk.h[2] = f2bf(y2); pk.h[3] = f2bf(y3);
    *(uint2*)(xn + (size_t)t * 1024 + d0) = pk.u;
  }

  // router: lane = e*8 + c; e-group of 8 lanes covers D via 32 float4 chunks
  const int e = lane >> 3, c = lane & 7;
  const float* wrow = rw + (size_t)e * 1024;
  float acc = 0.f;
#pragma unroll
  for (int i = 0; i < 32; ++i) {
    const int d4 = 4 * (c + 8 * i);
    const float4 wv = *(const float4*)(wrow + d4);
    const float4 xv = *(const float4*)(&xs[wave][d4]);
    acc += xv.x * wv.x + xv.y * wv.y + xv.z * wv.z + xv.w * wv.w;
  }
  acc += __shfl_xor(acc, 1, 64);
  acc += __shfl_xor(acc, 2, 64);
  acc += __shfl_xor(acc, 4, 64);
  const float logit = acc + rb[e];
  float l[8];
#pragma unroll
  for (int ee = 0; ee < 8; ++ee) l[ee] = __shfl(logit, ee * 8, 64);
  if (lane == 0) {
    int i0 = 0; float l0 = l[0];
#pragma unroll
    for (int k = 1; k < 8; ++k) if (l[k] > l0) { l0 = l[k]; i0 = k; }
    int i1 = -1; float l1 = -3.4e38f;
#pragma unroll
    for (int k = 0; k < 8; ++k) { if (k == i0) continue; if (l[k] > l1) { l1 = l[k]; i1 = k; } }
    float w0 = 1.0f / (1.0f + __expf(l1 - l0));
    tk_idx[2 * t] = i0; tk_idx[2 * t + 1] = i1;
    tk_w[2 * t] = w0; tk_w[2 * t + 1] = 1.0f - w0;
  }
}

// ---------------------------------------------------------------------------
// K2: single-block deterministic slot assignment (atomic-free).
// ---------------------------------------------------------------------------
__device__ __forceinline__ uint4 u4_add(uint4 a, uint4 b) {
  uint4 r; r.x = a.x + b.x; r.y = a.y + b.y; r.z = a.z + b.z; r.w = a.w + b.w; return r;
}
__device__ __forceinline__ uint4 u4_sub(uint4 a, uint4 b) {
  uint4 r; r.x = a.x - b.x; r.y = a.y - b.y; r.z = a.z - b.z; r.w = a.w - b.w; return r;
}

__global__ __launch_bounds__(256) void assign_k(
    const int* __restrict__ tk_idx, const float* __restrict__ tk_w,
    int* __restrict__ offs, int* __restrict__ slot_token,
    float* __restrict__ slot_w, int* __restrict__ slot_of)
{
  const int tid = threadIdx.x, lane = tid & 63, wave = tid >> 6;
  int eidx[32];
#pragma unroll
  for (int j = 0; j < 32; ++j) eidx[j] = tk_idx[tid * 32 + j];

  uint4 p = {0u, 0u, 0u, 0u};
#pragma unroll
  for (int j = 0; j < 32; ++j) {
    int e = eidx[j];
    unsigned inc = 1u << ((e & 1) * 16);
    int c = e >> 1;
    if (c == 0) p.x += inc; else if (c == 1) p.y += inc;
    else if (c == 2) p.z += inc; else p.w += inc;
  }
  const uint4 own = p;
#pragma unroll
  for (int o = 1; o < 64; o <<= 1) {
    uint4 t;
    t.x = (u32)__shfl_up((int)p.x, o, 64);
    t.y = (u32)__shfl_up((int)p.y, o, 64);
    t.z = (u32)__shfl_up((int)p.z, o, 64);
    t.w = (u32)__shfl_up((int)p.w, o, 64);
    if (lane >= o) p = u4_add(p, t);
  }
  __shared__ uint4 wtot[4];
  __shared__ int offs_s[9];
  if (lane == 63) wtot[wave] = p;
  __syncthreads();
  uint4 wbase = {0u, 0u, 0u, 0u};
  uint4 gtot = {0u, 0u, 0u, 0u};
#pragma unroll
  for (int w2 = 0; w2 < 4; ++w2) {
    uint4 t = wtot[w2];
    if (w2 < wave) wbase = u4_add(wbase, t);
    gtot = u4_add(gtot, t);
  }
  const uint4 excl = u4_sub(p, own);
  if (tid == 0) {
    int gtots[8] = { (int)(gtot.x & 0xffff), (int)(gtot.x >> 16),
                     (int)(gtot.y & 0xffff), (int)(gtot.y >> 16),
                     (int)(gtot.z & 0xffff), (int)(gtot.z >> 16),
                     (int)(gtot.w & 0xffff), (int)(gtot.w >> 16) };
    int a = 0;
#pragma unroll
    for (int e = 0; e < 8; ++e) { offs_s[e] = a; offs[e] = a; a += gtots[e]; }
    offs_s[8] = a; offs[8] = a;
  }
  __syncthreads();
  const uint4 pre = u4_add(wbase, excl);
  int base[8];
  base[0] = offs_s[0] + (int)(pre.x & 0xffff);
  base[1] = offs_s[1] + (int)(pre.x >> 16);
  base[2] = offs_s[2] + (int)(pre.y & 0xffff);
  base[3] = offs_s[3] + (int)(pre.y >> 16);
  base[4] = offs_s[4] + (int)(pre.z & 0xffff);
  base[5] = offs_s[5] + (int)(pre.z >> 16);
  base[6] = offs_s[6] + (int)(pre.w & 0xffff);
  base[7] = offs_s[7] + (int)(pre.w >> 16);
#pragma unroll
  for (int j = 0; j < 32; ++j) {
    int idx = tid * 32 + j;
    int e = eidx[j];
    int s = base[e]++;
    slot_token[s] = idx >> 1;
    slot_w[s] = tk_w[idx];
    slot_of[idx] = s;
  }
}

// ---------------------------------------------------------------------------
// Fused NT GEMM body (z=0 shared expert, z>0 routed segments).
// Round-7: XCD-AWARE TILE SWIZZLE. Grid (NT,32,9); XCD = linearId%8 = bx&7.
//   r=bx&7 (XCD), s=bx>>3:  m-tile = r + 8*(by>>3),  n-tile = s + (NT/8)*(by&7)
// -> each XCD keeps ONE 512KB A m-tile hot in its private L2 across 8-16
// consecutive blocks, and all 8 XCDs stream the same B n-tile concurrently
// (single HBM fetch, L3-shared). Round-6 FC2 FETCH was 217MB vs ~84MB unique
// because XCD = n-tile made every XCD stream the whole A through 4MB L2.
// K-loop: round-6 coalesced staging + double-buffered single barrier.
// ---------------------------------------------------------------------------
template <int N, int KD, int STAGE>
__device__ __forceinline__ void gemm_body(
    const u16* __restrict__ Abase, const u16* __restrict__ Bsh,
    const u16* __restrict__ Bex, const float* __restrict__ bias_sh,
    const float* __restrict__ bias_ex,
    u16* __restrict__ outH,
    const int* __restrict__ offs, const int* __restrict__ slot_token,
    const float* __restrict__ slot_w)
{
  const int tid = threadIdx.x;
  const int z = blockIdx.z;
  int off = 0, cnt = 4096, obase = 0;
  const u16* B = Bsh;
  const float* biasp = bias_sh;
  if (z > 0) {
    off = offs[z - 1]; cnt = offs[z] - off; obase = 4096 + off;
    B = Bex + (size_t)(z - 1) * N * KD;
    biasp = bias_ex + (size_t)(z - 1) * N;
  }
  constexpr int NT = N / 128;
  const int bx = blockIdx.x, by = blockIdx.y;
  const int r = bx & 7, sgl = bx >> 3;
  const int m0 = (r + 8 * (by >> 3)) * 128;
  if (m0 >= cnt) return;
  const int n0 = (sgl + (NT >> 3) * (by & 7)) * 128;

  __shared__ u16 lA[2][4096];
  __shared__ u16 lB[2][4096];

  const int rS = tid >> 2;          // staging row 0..63
  const int c8 = (tid & 3) * 8;     // staging col granule (8 bf16 = 16B)

  int ra0 = m0 + rS;      if (ra0 > cnt - 1) ra0 = cnt - 1;
  int ra1 = m0 + rS + 64; if (ra1 > cnt - 1) ra1 = cnt - 1;
  size_t arow0, arow1;
  if (STAGE == 1) {
    if (z == 0) { arow0 = (size_t)ra0; arow1 = (size_t)ra1; }
    else        { arow0 = (size_t)slot_token[off + ra0]; arow1 = (size_t)slot_token[off + ra1]; }
  } else {
    if (z == 0) { arow0 = (size_t)ra0; arow1 = (size_t)ra1; }
    else        { arow0 = (size_t)(4096 + off + ra0); arow1 = (size_t)(4096 + off + ra1); }
  }
  const u16* gA0 = Abase + arow0 * KD + c8;
  const u16* gA1 = Abase + arow1 * KD + c8;
  const u16* gB0 = B + (size_t)(n0 + rS) * KD + c8;
  const u16* gB1 = B + (size_t)(n0 + rS + 64) * KD + c8;

  const int wave = tid >> 6, lane = tid & 63;
  const int wr = wave >> 1, wc = wave & 1;
  const int fr = lane & 15, fq = lane >> 4;

  f32x4 acc[4][4];
  const f32x4 zero = {0.f, 0.f, 0.f, 0.f};
#pragma unroll
  for (int i = 0; i < 4; ++i)
#pragma unroll
    for (int n = 0; n < 4; ++n) acc[i][n] = zero;

  const int NK = KD / 32;
  {
    ASYNC_COPY16(gA0, &lA[0][0] + wave * 512);
    ASYNC_COPY16(gA1, &lA[0][0] + 2048 + wave * 512);
    ASYNC_COPY16(gB0, &lB[0][0] + wave * 512);
    ASYNC_COPY16(gB1, &lB[0][0] + 2048 + wave * 512);
    gA0 += 32; gA1 += 32; gB0 += 32; gB1 += 32;
  }

  for (int kb = 0; kb < NK; ++kb) {
    const int cur = kb & 1;
    __syncthreads();  // drains prefetch of cur; all reads of cur^1 are done
    if (kb + 1 < NK) {
      ASYNC_COPY16(gA0, &lA[cur ^ 1][0] + wave * 512);
      ASYNC_COPY16(gA1, &lA[cur ^ 1][0] + 2048 + wave * 512);
      ASYNC_COPY16(gB0, &lB[cur ^ 1][0] + wave * 512);
      ASYNC_COPY16(gB1, &lB[cur ^ 1][0] + 2048 + wave * 512);
      gA0 += 32; gA1 += 32; gB0 += 32; gB1 += 32;
    }
    const u16* rdA = &lA[cur][0] + (wr * 64 + fr) * 32 + fq * 8;
    const u16* rdB = &lB[cur][0] + (wc * 64 + fr) * 32 + fq * 8;
    bf16x8 af[4], bfv[4];
#pragma unroll
    for (int i = 0; i < 4; ++i) af[i] = *(const bf16x8*)(rdA + i * 16 * 32);
#pragma unroll
    for (int n = 0; n < 4; ++n) bfv[n] = *(const bf16x8*)(rdB + n * 16 * 32);
#pragma unroll
    for (int i = 0; i < 4; ++i)
#pragma unroll
      for (int n = 0; n < 4; ++n)
        acc[i][n] = __builtin_amdgcn_mfma_f32_16x16x32_bf16(af[i], bfv[n], acc[i][n], 0, 0, 0);
  }

  // epilogue: C/D layout col=lane&15, row=(lane>>4)*4+reg
  const int colBase = n0 + wc * 64;
#pragma unroll
  for (int i = 0; i < 4; ++i) {
    const int mlBase = m0 + wr * 64 + i * 16 + fq * 4;
#pragma unroll
    for (int rr = 0; rr < 4; ++rr) {
      const int ml = mlBase + rr;
      if (ml >= cnt) continue;
      const size_t orow = (size_t)(obase + ml) * N;
      float rwgt = (STAGE == 2) ? ((z == 0) ? (1.0f / 9.0f) : slot_w[off + ml]) : 1.f;
#pragma unroll
      for (int n = 0; n < 4; ++n) {
        const int col = colBase + n * 16 + fr;
        float v = acc[i][n][rr] + biasp[col];
        if (STAGE == 1) v = gelu_fast(v);
        else            v = v * rwgt;
        outH[orow + col] = f2bf(v);
      }
    }
  }
}

__global__ __launch_bounds__(256) void fc1_k(
    const u16* __restrict__ Abase, const u16* __restrict__ Bsh,
    const u16* __restrict__ Bex, const float* __restrict__ bias_sh,
    const float* __restrict__ bias_ex, u16* __restrict__ outH,
    const int* __restrict__ offs, const int* __restrict__ slot_token,
    const float* __restrict__ slot_w)
{
  gemm_body<2048, 1024, 1>(Abase, Bsh, Bex, bias_sh, bias_ex, outH, offs, slot_token, slot_w);
}

__global__ __launch_bounds__(256) void fc2_k(
    const u16* __restrict__ Abase, const u16* __restrict__ Bsh,
    const u16* __restrict__ Bex, const float* __restrict__ bias_sh,
    const float* __restrict__ bias_ex, u16* __restrict__ outH,
    const int* __restrict__ offs, const int* __restrict__ slot_token,
    const float* __restrict__ slot_w)
{
  gemm_body<1024, 2048, 2>(Abase, Bsh, Bex, bias_sh, bias_ex, outH, offs, slot_token, slot_w);
}

// ---------------------------------------------------------------------------
// K5: combine + LayerNorm, WAVE-PER-TOKEN (no barriers).
// ---------------------------------------------------------------------------
__global__ __launch_bounds__(256) void combine_ln2_k(
    const u16* __restrict__ sh_out, const u16* __restrict__ eout,
    const int* __restrict__ slot_of,
    const float* __restrict__ g2, const float* __restrict__ b2,
    float* __restrict__ out)
{
  const int wave = threadIdx.x >> 6, lane = threadIdx.x & 63;
  const int t = blockIdx.x * 4 + wave;
  const size_t s0 = (size_t)slot_of[2 * t], s1 = (size_t)slot_of[2 * t + 1];
  const u16* pa = sh_out + (size_t)t * 1024;
  const u16* p0 = eout + s0 * 1024;
  const u16* p1 = eout + s1 * 1024;
  float vv[16];
  float s = 0.f, q = 0.f;
#pragma unroll
  for (int j = 0; j < 4; ++j) {
    const int d0 = lane * 4 + j * 256;
    union { uint2 u; u16 h[4]; } a, c0, c1;
    a.u  = *(const uint2*)(pa + d0);
    c0.u = *(const uint2*)(p0 + d0);
    c1.u = *(const uint2*)(p1 + d0);
#pragma unroll
    for (int k = 0; k < 4; ++k) {
      float v = bf2f(a.h[k]) + bf2f(c0.h[k]) + bf2f(c1.h[k]);
      vv[4 * j + k] = v;
      s += v; q += v * v;
    }
  }
#pragma unroll
  for (int o = 32; o > 0; o >>= 1) { s += __shfl_down(s, o, 64); q += __shfl_down(q, o, 64); }
  s = __shfl(s, 0, 64); q = __shfl(q, 0, 64);
  const float mean = s * (1.0f / 1024.0f);
  const float rstd = rsqrtf(q * (1.0f / 1024.0f) - mean * mean + 1e-5f);
#pragma unroll
  for (int j = 0; j < 4; ++j) {
    const int d0 = lane * 4 + j * 256;
    const float4 gv = *(const float4*)(g2 + d0);
    const float4 bv = *(const float4*)(b2 + d0);
    float4 ov;
    ov.x = (vv[4 * j + 0] - mean) * rstd * gv.x + bv.x;
    ov.y = (vv[4 * j + 1] - mean) * rstd * gv.y + bv.y;
    ov.z = (vv[4 * j + 2] - mean) * rstd * gv.z + bv.z;
    ov.w = (vv[4 * j + 3] - mean) * rstd * gv.w + bv.w;
    *(float4*)(out + (size_t)t * 1024 + d0) = ov;
  }
}

// ---------------------------------------------------------------------------
extern "C" void kernel_launch(void* const* d_in, const int* in_sizes, int n_in,
                              void* d_out, int out_size, void* d_ws, size_t ws_size,
                              hipStream_t stream)
{
  const float* x     = (const float*)d_in[0];
  const float* ln1_g = (const float*)d_in[1];
  const float* ln1_b = (const float*)d_in[2];
  const float* rw    = (const float*)d_in[3];
  const float* rb    = (const float*)d_in[4];
  const float* sh_w1 = (const float*)d_in[5];
  const float* sh_b1 = (const float*)d_in[6];
  const float* sh_w2 = (const float*)d_in[7];
  const float* sh_b2 = (const float*)d_in[8];
  const float* e_w1  = (const float*)d_in[9];
  const float* e_b1  = (const float*)d_in[10];
  const float* e_w2  = (const float*)d_in[11];
  const float* e_b2  = (const float*)d_in[12];
  const float* ln2_g = (const float*)d_in[13];
  const float* ln2_b = (const float*)d_in[14];
  float* out = (float*)d_out;

  char* w = (char*)d_ws;
  u16*   x_norm = (u16*)(w + 0);              //  8 MiB  [4096,1024] bf16
  u16*   hid    = (u16*)(w + (8u << 20));     // 48 MiB  [12288,2048] bf16 (shared|slots)
  u16*   outb   = (u16*)(w + (56u << 20));    // 24 MiB  [12288,1024] bf16 (shared|slots)
  u16*   w1b    = (u16*)(w + (104u << 20));   //  4 MiB  [2048,1024]  (contig with below)
  u16*   w2b    = (u16*)(w + (108u << 20));   //  4 MiB  [1024,2048]
  u16*   ew1b   = (u16*)(w + (112u << 20));   // 32 MiB  [8,2048,1024]
  u16*   ew2b   = (u16*)(w + (144u << 20));   // 32 MiB  [8,1024,2048]
  char*  meta   = w + (176u << 20);
  int*   tk_idx     = (int*)(meta);
  float* tk_w       = (float*)(meta + (32u << 10));
  int*   slot_token = (int*)(meta + (64u << 10));
  float* slot_w     = (float*)(meta + (96u << 10));
  int*   slot_of    = (int*)(meta + (128u << 10));
  int*   offs       = (int*)(meta + (160u << 10)); // 9 ints

  cvt_all_k<<<18432, 256, 0, stream>>>(sh_w1, sh_w2, e_w1, e_w2, w1b);

  ln_router_k<<<1024, 256, 0, stream>>>(x, ln1_g, ln1_b, rw, rb, x_norm, tk_idx, tk_w);
  assign_k<<<1, 256, 0, stream>>>(tk_idx, tk_w, offs, slot_token, slot_w, slot_of);

  // FC1 (shared z=0 + experts z=1..8): -> fast GELU -> hid bf16
  fc1_k<<<dim3(16, 32, 9), 256, 0, stream>>>(
      x_norm, w1b, ew1b, sh_b1, e_b1, hid, offs, slot_token, nullptr);
  // FC2 (shared z=0 + experts z=1..8): -> scaled bf16 -> outb
  fc2_k<<<dim3(8, 32, 9), 256, 0, stream>>>(
      hid, w2b, ew2b, sh_b2, e_b2, outb, offs, slot_token, slot_w);

  combine_ln2_k<<<1024, 256, 0, stream>>>(outb, outb + (size_t)4096 * 1024,
                                          slot_of, ln2_g, ln2_b, out);
}